// Round 9
// baseline (980.341 us; speedup 1.0000x reference)
//
#include <hip/hip_runtime.h>
#include <hip/hip_bf16.h>

// GCN 3-layer forward on MI355X.
// h = bf16(dinv .* (a @ W))  (dense gemm, W in LDS, panel output)
// a = bf16(relu(dinv .* (h[i] + sum_e h[src_e]) + b))  (col-sliced gather)
// CSR via single-pass bucket binning (arena slots).
// KEY: gather kernels are column-sliced (8-col panels, slice = blockIdx&7
// -> XCD-pinned by round-robin dispatch) so each XCD's gather working set
// is n*16B = 1.6MB and fits its private 4MB L2. Panel layout keeps slice
// reads/writes contiguous and XCD-local (no cross-XCD false sharing).

#define BLOCK 256
#define NBUCKET 512
#define CHUNK 4096
#define SLOT 4608
#define MAX_NPB 256

typedef float f32x4 __attribute__((ext_vector_type(4)));

__device__ __forceinline__ float4 fma4(float s, float4 a, float4 b) {
  return make_float4(fmaf(s, a.x, b.x), fmaf(s, a.y, b.y),
                     fmaf(s, a.z, b.z), fmaf(s, a.w, b.w));
}

__device__ __forceinline__ unsigned int bf16r(float f) {
  unsigned int u = __float_as_uint(f);
  u += 0x7fffu + ((u >> 16) & 1u);
  return u >> 16;
}

// accumulate 8 bf16 (uint4) into two float4 accumulators
__device__ __forceinline__ void acc_bf8(float4& lo, float4& hi, uint4 u) {
  lo.x += __uint_as_float(u.x << 16);
  lo.y += __uint_as_float(u.x & 0xffff0000u);
  lo.z += __uint_as_float(u.y << 16);
  lo.w += __uint_as_float(u.y & 0xffff0000u);
  hi.x += __uint_as_float(u.z << 16);
  hi.y += __uint_as_float(u.z & 0xffff0000u);
  hi.z += __uint_as_float(u.w << 16);
  hi.w += __uint_as_float(u.w & 0xffff0000u);
}

// ---- CSR build (unchanged from R7/R8) ----

__global__ __launch_bounds__(BLOCK) void binning_kernel(
    const int* __restrict__ src, const int* __restrict__ dst,
    int* __restrict__ bcursor, int* __restrict__ binned, int e, int npb) {
  __shared__ int h[NBUCKET];
  __shared__ int base[NBUCKET];
  for (int i = threadIdx.x; i < NBUCKET; i += BLOCK) h[i] = 0;
  __syncthreads();
  const int cbase = blockIdx.x * CHUNK;
#pragma unroll
  for (int k = 0; k < CHUNK; k += BLOCK * 4) {
    int i = cbase + k + threadIdx.x * 4;
    if (i + 3 < e) {
      int4 d4 = *(const int4*)(dst + i);
      atomicAdd(&h[d4.x / npb], 1);
      atomicAdd(&h[d4.y / npb], 1);
      atomicAdd(&h[d4.z / npb], 1);
      atomicAdd(&h[d4.w / npb], 1);
    } else {
      for (int t = 0; t < 4; ++t)
        if (i + t < e) atomicAdd(&h[dst[i + t] / npb], 1);
    }
  }
  __syncthreads();
  for (int i = threadIdx.x; i < NBUCKET; i += BLOCK) {
    int c = h[i];
    base[i] = c ? atomicAdd(&bcursor[i], c) : 0;
    h[i] = 0;
  }
  __syncthreads();
#pragma unroll
  for (int k = 0; k < CHUNK; k += BLOCK * 4) {
    int i = cbase + k + threadIdx.x * 4;
    if (i + 3 < e) {
      int4 d4 = *(const int4*)(dst + i);
      int4 s4 = *(const int4*)(src + i);
      int b0 = d4.x / npb, b1 = d4.y / npb, b2 = d4.z / npb, b3 = d4.w / npb;
      int o0 = atomicAdd(&h[b0], 1);
      int o1 = atomicAdd(&h[b1], 1);
      int o2 = atomicAdd(&h[b2], 1);
      int o3 = atomicAdd(&h[b3], 1);
      binned[b0 * SLOT + base[b0] + o0] = s4.x | ((d4.x - b0 * npb) << 17);
      binned[b1 * SLOT + base[b1] + o1] = s4.y | ((d4.y - b1 * npb) << 17);
      binned[b2 * SLOT + base[b2] + o2] = s4.z | ((d4.z - b2 * npb) << 17);
      binned[b3 * SLOT + base[b3] + o3] = s4.w | ((d4.w - b3 * npb) << 17);
    } else {
      for (int t = 0; t < 4; ++t) {
        if (i + t < e) {
          int d = dst[i + t];
          int bkt = d / npb;
          int lofs = atomicAdd(&h[bkt], 1);
          binned[bkt * SLOT + base[bkt] + lofs] =
              src[i + t] | ((d - bkt * npb) << 17);
        }
      }
    }
  }
}

__global__ __launch_bounds__(BLOCK) void bucket_build(
    const int* __restrict__ binned, const int* __restrict__ bcursor,
    int* __restrict__ offs, int* __restrict__ cnt, float* __restrict__ dinv,
    int* __restrict__ csr_src, int n, int npb) {
  __shared__ int nhist[MAX_NPB];
  __shared__ int noff[MAX_NPB];
  __shared__ int lcsr[SLOT];
  const int b = blockIdx.x;
  const int node_base = b * npb;
  const int nodes = min(npb, n - node_base);
  if (nodes <= 0) return;
  const int ebase = b * SLOT;
  const int ecnt = bcursor[b];
  for (int i = threadIdx.x; i < npb; i += BLOCK) nhist[i] = 0;
  __syncthreads();
  for (int i = threadIdx.x; i < ecnt; i += BLOCK)
    atomicAdd(&nhist[binned[ebase + i] >> 17], 1);
  __syncthreads();
  if (threadIdx.x < 64) {
    const int lane = threadIdx.x;
    const int bi = lane * 4;
    int v0 = (bi + 0 < nodes) ? nhist[bi + 0] : 0;
    int v1 = (bi + 1 < nodes) ? nhist[bi + 1] : 0;
    int v2 = (bi + 2 < nodes) ? nhist[bi + 2] : 0;
    int v3 = (bi + 3 < nodes) ? nhist[bi + 3] : 0;
    int tsum = v0 + v1 + v2 + v3;
    int s = tsum;
#pragma unroll
    for (int o = 1; o < 64; o <<= 1) {
      int u = __shfl_up(s, o, 64);
      if (lane >= o) s += u;
    }
    int texcl = s - tsum;
    if (bi + 0 < nodes) noff[bi + 0] = texcl;
    if (bi + 1 < nodes) noff[bi + 1] = texcl + v0;
    if (bi + 2 < nodes) noff[bi + 2] = texcl + v0 + v1;
    if (bi + 3 < nodes) noff[bi + 3] = texcl + v0 + v1 + v2;
  }
  __syncthreads();
  for (int i = threadIdx.x; i < nodes; i += BLOCK) {
    int c = nhist[i];
    offs[node_base + i] = ebase + noff[i];
    cnt[node_base + i] = c;
    dinv[node_base + i] = rsqrtf((float)(c + 1));
  }
  __syncthreads();
  for (int i = threadIdx.x; i < ecnt; i += BLOCK) {
    int v = binned[ebase + i];
    int pos = atomicAdd(&noff[v >> 17], 1);
    lcsr[pos] = v & 0x1ffff;
  }
  __syncthreads();
  for (int i = threadIdx.x; i < ecnt; i += BLOCK)
    csr_src[ebase + i] = lcsr[i];
}

// ---- dense gemms (panel bf16 output, dinv-folded) ----

// gemm1: fp32 x (row-major n x 64) @ W(64x64) -> 8-col bf16 panels.
// 2 rows x 8 cols per thread; 64 rows/block.
__global__ __launch_bounds__(BLOCK) void gemm1_kernel(
    const float* __restrict__ x, const float* __restrict__ W,
    const float* __restrict__ dinv, unsigned short* __restrict__ hout, int n) {
  __shared__ float Ws[64 * 64];
  for (int i = threadIdx.x * 4; i < 64 * 64; i += BLOCK * 4)
    *(float4*)(Ws + i) = *(const float4*)(W + i);
  __syncthreads();
  const int cg = threadIdx.x & 7;
  const int rloc = threadIdx.x >> 3;
  const int r0 = blockIdx.x * 64 + rloc;
  const int r1 = r0 + 32;
  const int rc0 = min(r0, n - 1), rc1 = min(r1, n - 1);
  float4 a00 = make_float4(0.f, 0.f, 0.f, 0.f);
  float4 a01 = a00, a10 = a00, a11 = a00;
  const int c8 = cg * 8;
#pragma unroll
  for (int k = 0; k < 64; k += 4) {
    float4 x0 = *(const float4*)(x + (size_t)rc0 * 64 + k);
    float4 x1 = *(const float4*)(x + (size_t)rc1 * 64 + k);
#pragma unroll
    for (int kk = 0; kk < 4; ++kk) {
      float4 w0 = *(const float4*)(Ws + (k + kk) * 64 + c8);
      float4 w1 = *(const float4*)(Ws + (k + kk) * 64 + c8 + 4);
      float s0 = (kk == 0) ? x0.x : (kk == 1) ? x0.y : (kk == 2) ? x0.z : x0.w;
      float s1 = (kk == 0) ? x1.x : (kk == 1) ? x1.y : (kk == 2) ? x1.z : x1.w;
      a00 = fma4(s0, w0, a00);
      a01 = fma4(s0, w1, a01);
      a10 = fma4(s1, w0, a10);
      a11 = fma4(s1, w1, a11);
    }
  }
  const size_t pstride = (size_t)n * 8;
  if (r0 < n) {
    float d = dinv[r0];
    uint4 p;
    p.x = bf16r(d * a00.x) | (bf16r(d * a00.y) << 16);
    p.y = bf16r(d * a00.z) | (bf16r(d * a00.w) << 16);
    p.z = bf16r(d * a01.x) | (bf16r(d * a01.y) << 16);
    p.w = bf16r(d * a01.z) | (bf16r(d * a01.w) << 16);
    *(uint4*)(hout + cg * pstride + (size_t)r0 * 8) = p;
  }
  if (r1 < n) {
    float d = dinv[r1];
    uint4 p;
    p.x = bf16r(d * a10.x) | (bf16r(d * a10.y) << 16);
    p.y = bf16r(d * a10.z) | (bf16r(d * a10.w) << 16);
    p.z = bf16r(d * a11.x) | (bf16r(d * a11.y) << 16);
    p.w = bf16r(d * a11.z) | (bf16r(d * a11.w) << 16);
    *(uint4*)(hout + cg * pstride + (size_t)r1 * 8) = p;
  }
}

// gemmB: bf16 8-col panels in (n x 64) @ W(64 x FOUT) -> bf16 panels out.
// FOUT=64 -> 8-col out panels; FOUT=32 -> 16-col out panels.
template <int FOUT>
__global__ __launch_bounds__(BLOCK) void gemmB_kernel(
    const unsigned short* __restrict__ ain, const float* __restrict__ W,
    const float* __restrict__ dinv, unsigned short* __restrict__ hout, int n) {
  __shared__ float Ws[64 * FOUT];
  for (int i = threadIdx.x * 4; i < 64 * FOUT; i += BLOCK * 4)
    *(float4*)(Ws + i) = *(const float4*)(W + i);
  __syncthreads();
  constexpr int CG = FOUT / 8;            // out col-groups
  constexpr int RPB = 2 * (BLOCK / CG);   // rows per block
  const int cg = threadIdx.x & (CG - 1);
  const int rloc = threadIdx.x / CG;
  const int r0 = blockIdx.x * RPB + rloc;
  const int r1 = r0 + RPB / 2;
  const int rc0 = min(r0, n - 1), rc1 = min(r1, n - 1);
  const size_t pin = (size_t)n * 8;
  float4 a00 = make_float4(0.f, 0.f, 0.f, 0.f);
  float4 a01 = a00, a10 = a00, a11 = a00;
  const int c8 = cg * 8;
#pragma unroll
  for (int p = 0; p < 8; ++p) {
    uint4 u0 = *(const uint4*)(ain + p * pin + (size_t)rc0 * 8);
    uint4 u1 = *(const uint4*)(ain + p * pin + (size_t)rc1 * 8);
    float x0[8], x1[8];
    x0[0] = __uint_as_float(u0.x << 16); x0[1] = __uint_as_float(u0.x & 0xffff0000u);
    x0[2] = __uint_as_float(u0.y << 16); x0[3] = __uint_as_float(u0.y & 0xffff0000u);
    x0[4] = __uint_as_float(u0.z << 16); x0[5] = __uint_as_float(u0.z & 0xffff0000u);
    x0[6] = __uint_as_float(u0.w << 16); x0[7] = __uint_as_float(u0.w & 0xffff0000u);
    x1[0] = __uint_as_float(u1.x << 16); x1[1] = __uint_as_float(u1.x & 0xffff0000u);
    x1[2] = __uint_as_float(u1.y << 16); x1[3] = __uint_as_float(u1.y & 0xffff0000u);
    x1[4] = __uint_as_float(u1.z << 16); x1[5] = __uint_as_float(u1.z & 0xffff0000u);
    x1[6] = __uint_as_float(u1.w << 16); x1[7] = __uint_as_float(u1.w & 0xffff0000u);
#pragma unroll
    for (int kk = 0; kk < 8; ++kk) {
      const int k = p * 8 + kk;
      float4 w0 = *(const float4*)(Ws + k * FOUT + c8);
      float4 w1 = *(const float4*)(Ws + k * FOUT + c8 + 4);
      a00 = fma4(x0[kk], w0, a00);
      a01 = fma4(x0[kk], w1, a01);
      a10 = fma4(x1[kk], w0, a10);
      a11 = fma4(x1[kk], w1, a11);
    }
  }
  // output panel addressing
  auto store = [&](int r, float4 lo, float4 hi) {
    float d = dinv[r];
    uint4 p;
    p.x = bf16r(d * lo.x) | (bf16r(d * lo.y) << 16);
    p.y = bf16r(d * lo.z) | (bf16r(d * lo.w) << 16);
    p.z = bf16r(d * hi.x) | (bf16r(d * hi.y) << 16);
    p.w = bf16r(d * hi.z) | (bf16r(d * hi.w) << 16);
    if (FOUT == 64) {
      *(uint4*)(hout + cg * ((size_t)n * 8) + (size_t)r * 8) = p;
    } else {
      // 16-col panels: panel = cg>>1, inner offset (cg&1)*8
      *(uint4*)(hout + (cg >> 1) * ((size_t)n * 16) + (size_t)r * 16 +
                (cg & 1) * 8) = p;
    }
  };
  if (r0 < n) store(r0, a00, a01);
  if (r1 < n) store(r1, a10, a11);
}

// ---- col-sliced gathers ----

// agg8: slice s = blockIdx&7 (XCD-pinned), 1 thread/node, 8 bf16 cols.
// a_out[s][node] = bf16(relu(dinv*(h[s][node] + sum h[s][src]) + b[s*8..]))
__global__ __launch_bounds__(BLOCK) void agg8_kernel(
    const unsigned short* __restrict__ hin, const int* __restrict__ csr_src,
    const int* __restrict__ offs, const int* __restrict__ cnt,
    const float* __restrict__ dinv, const float* __restrict__ bias,
    unsigned short* __restrict__ aout, int n) {
  const int s = blockIdx.x & 7;
  const int node = (blockIdx.x >> 3) * BLOCK + threadIdx.x;
  if (node >= n) return;
  const unsigned short* hp = hin + (size_t)s * n * 8;
  const int start = offs[node];
  const int cn = cnt[node];
  float4 l0 = make_float4(0.f, 0.f, 0.f, 0.f), h0 = l0;
  float4 l1 = l0, h1 = l0, l2 = l0, h2 = l0, l3 = l0, h3 = l0;
  acc_bf8(l0, h0, *(const uint4*)(hp + (size_t)node * 8));  // self-loop
  int j = 0;
  for (; j + 4 <= cn; j += 4) {
    int s0 = csr_src[start + j + 0];
    int s1 = csr_src[start + j + 1];
    int s2 = csr_src[start + j + 2];
    int s3 = csr_src[start + j + 3];
    uint4 u0 = *(const uint4*)(hp + (size_t)s0 * 8);
    uint4 u1 = *(const uint4*)(hp + (size_t)s1 * 8);
    uint4 u2 = *(const uint4*)(hp + (size_t)s2 * 8);
    uint4 u3 = *(const uint4*)(hp + (size_t)s3 * 8);
    acc_bf8(l0, h0, u0);
    acc_bf8(l1, h1, u1);
    acc_bf8(l2, h2, u2);
    acc_bf8(l3, h3, u3);
  }
  if (j + 2 <= cn) {
    int s0 = csr_src[start + j + 0];
    int s1 = csr_src[start + j + 1];
    uint4 u0 = *(const uint4*)(hp + (size_t)s0 * 8);
    uint4 u1 = *(const uint4*)(hp + (size_t)s1 * 8);
    acc_bf8(l1, h1, u0);
    acc_bf8(l2, h2, u1);
    j += 2;
  }
  if (j < cn) {
    int s0 = csr_src[start + j];
    acc_bf8(l3, h3, *(const uint4*)(hp + (size_t)s0 * 8));
  }
  float4 alo = make_float4((l0.x + l1.x) + (l2.x + l3.x),
                           (l0.y + l1.y) + (l2.y + l3.y),
                           (l0.z + l1.z) + (l2.z + l3.z),
                           (l0.w + l1.w) + (l2.w + l3.w));
  float4 ahi = make_float4((h0.x + h1.x) + (h2.x + h3.x),
                           (h0.y + h1.y) + (h2.y + h3.y),
                           (h0.z + h1.z) + (h2.z + h3.z),
                           (h0.w + h1.w) + (h2.w + h3.w));
  float d = dinv[node];
  float4 blo = *(const float4*)(bias + s * 8);
  float4 bhi = *(const float4*)(bias + s * 8 + 4);
  uint4 p;
  p.x = bf16r(fmaxf(fmaf(d, alo.x, blo.x), 0.f)) |
        (bf16r(fmaxf(fmaf(d, alo.y, blo.y), 0.f)) << 16);
  p.y = bf16r(fmaxf(fmaf(d, alo.z, blo.z), 0.f)) |
        (bf16r(fmaxf(fmaf(d, alo.w, blo.w), 0.f)) << 16);
  p.z = bf16r(fmaxf(fmaf(d, ahi.x, bhi.x), 0.f)) |
        (bf16r(fmaxf(fmaf(d, ahi.y, bhi.y), 0.f)) << 16);
  p.w = bf16r(fmaxf(fmaf(d, ahi.z, bhi.z), 0.f)) |
        (bf16r(fmaxf(fmaf(d, ahi.w, bhi.w), 0.f)) << 16);
  *(uint4*)(aout + (size_t)s * n * 8 + (size_t)node * 8) = p;
}

// agg16F: final layer. 16-col slices (s = blockIdx&1), fp32 row-major out.
__global__ __launch_bounds__(BLOCK) void agg16f_kernel(
    const unsigned short* __restrict__ hin, const int* __restrict__ csr_src,
    const int* __restrict__ offs, const int* __restrict__ cnt,
    const float* __restrict__ dinv, const float* __restrict__ bias,
    float* __restrict__ out, int n) {
  const int s = blockIdx.x & 1;
  const int node = (blockIdx.x >> 1) * BLOCK + threadIdx.x;
  if (node >= n) return;
  const unsigned short* hp = hin + (size_t)s * n * 16;
  const int start = offs[node];
  const int cn = cnt[node];
  float4 al0 = make_float4(0.f, 0.f, 0.f, 0.f), ah0 = al0;
  float4 bl0 = al0, bh0 = al0;  // second 8 cols
  float4 al1 = al0, ah1 = al0, bl1 = al0, bh1 = al0;
  {
    uint4 u0 = *(const uint4*)(hp + (size_t)node * 16);
    uint4 u1 = *(const uint4*)(hp + (size_t)node * 16 + 8);
    acc_bf8(al0, ah0, u0);
    acc_bf8(bl0, bh0, u1);
  }
  int j = 0;
  for (; j + 2 <= cn; j += 2) {
    int s0 = csr_src[start + j + 0];
    int s1 = csr_src[start + j + 1];
    uint4 u00 = *(const uint4*)(hp + (size_t)s0 * 16);
    uint4 u01 = *(const uint4*)(hp + (size_t)s0 * 16 + 8);
    uint4 u10 = *(const uint4*)(hp + (size_t)s1 * 16);
    uint4 u11 = *(const uint4*)(hp + (size_t)s1 * 16 + 8);
    acc_bf8(al0, ah0, u00);
    acc_bf8(bl0, bh0, u01);
    acc_bf8(al1, ah1, u10);
    acc_bf8(bl1, bh1, u11);
  }
  if (j < cn) {
    int s0 = csr_src[start + j];
    uint4 u0 = *(const uint4*)(hp + (size_t)s0 * 16);
    uint4 u1 = *(const uint4*)(hp + (size_t)s0 * 16 + 8);
    acc_bf8(al1, ah1, u0);
    acc_bf8(bl1, bh1, u1);
  }
  float4 A = make_float4(al0.x + al1.x, al0.y + al1.y, al0.z + al1.z, al0.w + al1.w);
  float4 B = make_float4(ah0.x + ah1.x, ah0.y + ah1.y, ah0.z + ah1.z, ah0.w + ah1.w);
  float4 C = make_float4(bl0.x + bl1.x, bl0.y + bl1.y, bl0.z + bl1.z, bl0.w + bl1.w);
  float4 D = make_float4(bh0.x + bh1.x, bh0.y + bh1.y, bh0.z + bh1.z, bh0.w + bh1.w);
  float d = dinv[node];
  const float* bp = bias + s * 16;
  float4 b0 = *(const float4*)(bp);
  float4 b1 = *(const float4*)(bp + 4);
  float4 b2 = *(const float4*)(bp + 8);
  float4 b3 = *(const float4*)(bp + 12);
  f32x4 v0 = {fmaf(d, A.x, b0.x), fmaf(d, A.y, b0.y), fmaf(d, A.z, b0.z), fmaf(d, A.w, b0.w)};
  f32x4 v1 = {fmaf(d, B.x, b1.x), fmaf(d, B.y, b1.y), fmaf(d, B.z, b1.z), fmaf(d, B.w, b1.w)};
  f32x4 v2 = {fmaf(d, C.x, b2.x), fmaf(d, C.y, b2.y), fmaf(d, C.z, b2.z), fmaf(d, C.w, b2.w)};
  f32x4 v3 = {fmaf(d, D.x, b3.x), fmaf(d, D.y, b3.y), fmaf(d, D.z, b3.z), fmaf(d, D.w, b3.w)};
  float* op = out + (size_t)node * 32 + s * 16;
  __builtin_nontemporal_store(v0, (f32x4*)op);
  __builtin_nontemporal_store(v1, (f32x4*)(op + 4));
  __builtin_nontemporal_store(v2, (f32x4*)(op + 8));
  __builtin_nontemporal_store(v3, (f32x4*)(op + 12));
}

static inline size_t align_up(size_t v, size_t a) { return (v + a - 1) & ~(a - 1); }

extern "C" void kernel_launch(void* const* d_in, const int* in_sizes, int n_in,
                              void* d_out, int out_size, void* d_ws, size_t ws_size,
                              hipStream_t stream) {
  const float* x = (const float*)d_in[0];
  const int* edge_index = (const int*)d_in[1];
  const float* W1 = (const float*)d_in[2];
  const float* b1 = (const float*)d_in[3];
  const float* W2 = (const float*)d_in[4];
  const float* b2 = (const float*)d_in[5];
  const float* W3 = (const float*)d_in[6];
  const float* b3 = (const float*)d_in[7];
  float* out = (float*)d_out;

  const int n = in_sizes[0] / 64;       // 100000
  const int e = in_sizes[1] / 2;        // 1600000
  const int* e_src = edge_index;
  const int* e_dst = edge_index + e;
  const int npb = (n + NBUCKET - 1) / NBUCKET;  // 196

  char* ws = (char*)d_ws;
  size_t off = 0;
  int* bcursor = (int*)(ws + off); off = align_up(off + NBUCKET * 4, 512);
  int* offs    = (int*)(ws + off); off = align_up(off + (size_t)n * 4, 512);
  int* cnt     = (int*)(ws + off); off = align_up(off + (size_t)n * 4, 512);
  float* dinv  = (float*)(ws + off); off = align_up(off + (size_t)n * 4, 512);
  int* binned  = (int*)(ws + off); off = align_up(off + (size_t)NBUCKET * SLOT * 4, 512);
  int* csr_src = (int*)(ws + off); off = align_up(off + (size_t)NBUCKET * SLOT * 4, 512);
  unsigned short* hbuf = (unsigned short*)(ws + off);   // h panels (n x 64)
  off = align_up(off + (size_t)n * 64 * 2, 512);
  unsigned short* abuf = (unsigned short*)(ws + off);   // a panels (n x 64)
  off = align_up(off + (size_t)n * 64 * 2, 512);
  unsigned short* h3buf = (unsigned short*)(ws + off);  // h3 panels (n x 32)
  off = align_up(off + (size_t)n * 32 * 2, 512);
  (void)ws_size;

  const int gC = (e + CHUNK - 1) / CHUNK;
  const int ntile = (n + BLOCK - 1) / BLOCK;

  hipMemsetAsync(bcursor, 0, NBUCKET * 4, stream);
  binning_kernel<<<gC, BLOCK, 0, stream>>>(e_src, e_dst, bcursor, binned, e, npb);
  bucket_build<<<NBUCKET, BLOCK, 0, stream>>>(binned, bcursor, offs, cnt, dinv,
                                              csr_src, n, npb);

  // L1: gemm x@W1 -> h panels; agg -> a panels
  gemm1_kernel<<<(n + 63) / 64, BLOCK, 0, stream>>>(x, W1, dinv, hbuf, n);
  agg8_kernel<<<ntile * 8, BLOCK, 0, stream>>>(hbuf, csr_src, offs, cnt, dinv,
                                               b1, abuf, n);
  // L2: gemm a@W2 -> h panels; agg -> a panels (reuse buffers ping-pong)
  gemmB_kernel<64><<<(n + 63) / 64, BLOCK, 0, stream>>>(abuf, W2, dinv, hbuf, n);
  agg8_kernel<<<ntile * 8, BLOCK, 0, stream>>>(hbuf, csr_src, offs, cnt, dinv,
                                               b2, abuf, n);
  // L3: gemm a@W3 -> h3 (16-col panels); final agg -> fp32 out
  gemmB_kernel<32><<<(n + 127) / 128, BLOCK, 0, stream>>>(abuf, W3, dinv, h3buf, n);
  agg16f_kernel<<<ntile * 2, BLOCK, 0, stream>>>(h3buf, csr_src, offs, cnt,
                                                 dinv, b3, out, n);
}

// Round 10
// 251.435 us; speedup vs baseline: 3.8990x; 3.8990x over previous
//
#include <hip/hip_runtime.h>
#include <hip/hip_bf16.h>

// GCN 3-layer forward on MI355X.  (R7 structure + R8's split-half fused64)
// h' = bf16( dinv .* (x @ W) );  out = relu(dinv .* (h'[i]+sum h'[src]) + b)
// CSR via single-pass bucket binning (arena slots).
// fused64: 16 lanes/node (8 col-lanes x 2 neighbor-halves, shfl_xor join).
// fused32/agg3: 8(4) lanes/node, x4-unrolled gather (R7's measured best).

#define BLOCK 256
#define NBUCKET 512
#define CHUNK 4096
#define SLOT 4608
#define MAX_NPB 256

typedef float f32x4 __attribute__((ext_vector_type(4)));

__device__ __forceinline__ float4 fma4(float s, float4 a, float4 b) {
  return make_float4(fmaf(s, a.x, b.x), fmaf(s, a.y, b.y),
                     fmaf(s, a.z, b.z), fmaf(s, a.w, b.w));
}

__device__ __forceinline__ unsigned int bf16r(float f) {
  unsigned int u = __float_as_uint(f);
  u += 0x7fffu + ((u >> 16) & 1u);
  return u >> 16;
}

__device__ __forceinline__ void acc_bf8(float4& lo, float4& hi, uint4 u) {
  lo.x += __uint_as_float(u.x << 16);
  lo.y += __uint_as_float(u.x & 0xffff0000u);
  lo.z += __uint_as_float(u.y << 16);
  lo.w += __uint_as_float(u.y & 0xffff0000u);
  hi.x += __uint_as_float(u.z << 16);
  hi.y += __uint_as_float(u.z & 0xffff0000u);
  hi.z += __uint_as_float(u.w << 16);
  hi.w += __uint_as_float(u.w & 0xffff0000u);
}

// ---- CSR build ----

__global__ __launch_bounds__(BLOCK) void binning_kernel(
    const int* __restrict__ src, const int* __restrict__ dst,
    int* __restrict__ bcursor, int* __restrict__ binned, int e, int npb) {
  __shared__ int h[NBUCKET];
  __shared__ int base[NBUCKET];
  for (int i = threadIdx.x; i < NBUCKET; i += BLOCK) h[i] = 0;
  __syncthreads();
  const int cbase = blockIdx.x * CHUNK;
#pragma unroll
  for (int k = 0; k < CHUNK; k += BLOCK * 4) {
    int i = cbase + k + threadIdx.x * 4;
    if (i + 3 < e) {
      int4 d4 = *(const int4*)(dst + i);
      atomicAdd(&h[d4.x / npb], 1);
      atomicAdd(&h[d4.y / npb], 1);
      atomicAdd(&h[d4.z / npb], 1);
      atomicAdd(&h[d4.w / npb], 1);
    } else {
      for (int t = 0; t < 4; ++t)
        if (i + t < e) atomicAdd(&h[dst[i + t] / npb], 1);
    }
  }
  __syncthreads();
  for (int i = threadIdx.x; i < NBUCKET; i += BLOCK) {
    int c = h[i];
    base[i] = c ? atomicAdd(&bcursor[i], c) : 0;
    h[i] = 0;
  }
  __syncthreads();
#pragma unroll
  for (int k = 0; k < CHUNK; k += BLOCK * 4) {
    int i = cbase + k + threadIdx.x * 4;
    if (i + 3 < e) {
      int4 d4 = *(const int4*)(dst + i);
      int4 s4 = *(const int4*)(src + i);
      int b0 = d4.x / npb, b1 = d4.y / npb, b2 = d4.z / npb, b3 = d4.w / npb;
      int o0 = atomicAdd(&h[b0], 1);
      int o1 = atomicAdd(&h[b1], 1);
      int o2 = atomicAdd(&h[b2], 1);
      int o3 = atomicAdd(&h[b3], 1);
      binned[b0 * SLOT + base[b0] + o0] = s4.x | ((d4.x - b0 * npb) << 17);
      binned[b1 * SLOT + base[b1] + o1] = s4.y | ((d4.y - b1 * npb) << 17);
      binned[b2 * SLOT + base[b2] + o2] = s4.z | ((d4.z - b2 * npb) << 17);
      binned[b3 * SLOT + base[b3] + o3] = s4.w | ((d4.w - b3 * npb) << 17);
    } else {
      for (int t = 0; t < 4; ++t) {
        if (i + t < e) {
          int d = dst[i + t];
          int bkt = d / npb;
          int lofs = atomicAdd(&h[bkt], 1);
          binned[bkt * SLOT + base[bkt] + lofs] =
              src[i + t] | ((d - bkt * npb) << 17);
        }
      }
    }
  }
}

__global__ __launch_bounds__(BLOCK) void bucket_build(
    const int* __restrict__ binned, const int* __restrict__ bcursor,
    int* __restrict__ offs, int* __restrict__ cnt, float* __restrict__ dinv,
    int* __restrict__ csr_src, int n, int npb) {
  __shared__ int nhist[MAX_NPB];
  __shared__ int noff[MAX_NPB];
  __shared__ int lcsr[SLOT];
  const int b = blockIdx.x;
  const int node_base = b * npb;
  const int nodes = min(npb, n - node_base);
  if (nodes <= 0) return;
  const int ebase = b * SLOT;
  const int ecnt = bcursor[b];
  for (int i = threadIdx.x; i < npb; i += BLOCK) nhist[i] = 0;
  __syncthreads();
  for (int i = threadIdx.x; i < ecnt; i += BLOCK)
    atomicAdd(&nhist[binned[ebase + i] >> 17], 1);
  __syncthreads();
  if (threadIdx.x < 64) {
    const int lane = threadIdx.x;
    const int bi = lane * 4;
    int v0 = (bi + 0 < nodes) ? nhist[bi + 0] : 0;
    int v1 = (bi + 1 < nodes) ? nhist[bi + 1] : 0;
    int v2 = (bi + 2 < nodes) ? nhist[bi + 2] : 0;
    int v3 = (bi + 3 < nodes) ? nhist[bi + 3] : 0;
    int tsum = v0 + v1 + v2 + v3;
    int s = tsum;
#pragma unroll
    for (int o = 1; o < 64; o <<= 1) {
      int u = __shfl_up(s, o, 64);
      if (lane >= o) s += u;
    }
    int texcl = s - tsum;
    if (bi + 0 < nodes) noff[bi + 0] = texcl;
    if (bi + 1 < nodes) noff[bi + 1] = texcl + v0;
    if (bi + 2 < nodes) noff[bi + 2] = texcl + v0 + v1;
    if (bi + 3 < nodes) noff[bi + 3] = texcl + v0 + v1 + v2;
  }
  __syncthreads();
  for (int i = threadIdx.x; i < nodes; i += BLOCK) {
    int c = nhist[i];
    offs[node_base + i] = ebase + noff[i];
    cnt[node_base + i] = c;
    dinv[node_base + i] = rsqrtf((float)(c + 1));
  }
  __syncthreads();
  for (int i = threadIdx.x; i < ecnt; i += BLOCK) {
    int v = binned[ebase + i];
    int pos = atomicAdd(&noff[v >> 17], 1);
    lcsr[pos] = v & 0x1ffff;
  }
  __syncthreads();
  for (int i = threadIdx.x; i < ecnt; i += BLOCK)
    csr_src[ebase + i] = lcsr[i];
}

// ---- dense layers ----

// Layer-1 GEMM: 1 row x 4 cols/thread, W in LDS.
__global__ __launch_bounds__(BLOCK) void gemm1_kernel(
    const float* __restrict__ x, const float* __restrict__ W,
    const float* __restrict__ dinv, unsigned short* __restrict__ hbf, int n) {
  __shared__ float Ws[64 * 64];
  for (int i = threadIdx.x * 4; i < 64 * 64; i += BLOCK * 4)
    *(float4*)(Ws + i) = *(const float4*)(W + i);
  __syncthreads();
  const int row = blockIdx.x * 16 + (int)(threadIdx.x >> 4);
  const int c4 = (threadIdx.x & 15) * 4;
  if (row >= n) return;
  const float* xr = x + (size_t)row * 64;
  float4 acc = make_float4(0.f, 0.f, 0.f, 0.f);
#pragma unroll
  for (int k = 0; k < 64; k += 4) {
    f32x4 xn = __builtin_nontemporal_load((const f32x4*)(xr + k));
    float4 w0 = *(const float4*)(Ws + (k + 0) * 64 + c4);
    float4 w1 = *(const float4*)(Ws + (k + 1) * 64 + c4);
    float4 w2 = *(const float4*)(Ws + (k + 2) * 64 + c4);
    float4 w3 = *(const float4*)(Ws + (k + 3) * 64 + c4);
    acc = fma4(xn.x, w0, acc);
    acc = fma4(xn.y, w1, acc);
    acc = fma4(xn.z, w2, acc);
    acc = fma4(xn.w, w3, acc);
  }
  float d = dinv[row];
  uint2 packed;
  packed.x = bf16r(d * acc.x) | (bf16r(d * acc.y) << 16);
  packed.y = bf16r(d * acc.z) | (bf16r(d * acc.w) << 16);
  *(uint2*)(hbf + (size_t)row * 64 + c4) = packed;
}

// Fused layer 1->2: agg (64, relu, b) -> gemm (64->64) -> bf16.
// 16 lanes/node = 8 col-lanes x 2 neighbor-halves; 16 nodes/block. [R8: 49us]
__global__ __launch_bounds__(BLOCK) void fused_agg_gemm64(
    const unsigned short* __restrict__ hin, const int* __restrict__ csr_src,
    const int* __restrict__ offs, const int* __restrict__ cnt,
    const float* __restrict__ dinv, const float* __restrict__ bias,
    const float* __restrict__ Wn, unsigned short* __restrict__ hout, int n) {
  __shared__ float Ws[64 * 64];
  __shared__ float vrow[16][68];  // +4 pad
  for (int i = threadIdx.x * 4; i < 64 * 64; i += BLOCK * 4)
    *(float4*)(Ws + i) = *(const float4*)(Wn + i);
  __syncthreads();
  const int g = threadIdx.x >> 4;
  const int lane16 = threadIdx.x & 15;
  const int colgrp = lane16 & 7;
  const int half = lane16 >> 3;
  const int c8 = colgrp * 8;
  const int node = blockIdx.x * 16 + g;
  const bool valid = node < n;
  float dnode = 0.f;
  if (valid) {
    const int start = offs[node];
    const int cn = cnt[node];
    const unsigned short* hcol = hin + c8;
    float4 l0 = make_float4(0.f, 0.f, 0.f, 0.f), h0 = l0;
    float4 l1 = l0, h1 = l0, l2 = l0, h2 = l0, l3 = l0, h3 = l0;
    if (half == 0)
      acc_bf8(l0, h0, *(const uint4*)(hcol + (size_t)node * 64));  // self
    int j = half * 4;
    for (; j + 4 <= cn; j += 8) {
      int s0 = csr_src[start + j + 0];
      int s1 = csr_src[start + j + 1];
      int s2 = csr_src[start + j + 2];
      int s3 = csr_src[start + j + 3];
      uint4 u0 = *(const uint4*)(hcol + (size_t)s0 * 64);
      uint4 u1 = *(const uint4*)(hcol + (size_t)s1 * 64);
      uint4 u2 = *(const uint4*)(hcol + (size_t)s2 * 64);
      uint4 u3 = *(const uint4*)(hcol + (size_t)s3 * 64);
      acc_bf8(l0, h0, u0);
      acc_bf8(l1, h1, u1);
      acc_bf8(l2, h2, u2);
      acc_bf8(l3, h3, u3);
    }
    if (j < cn) {  // partial chunk, at most 3 entries
      int rem = cn - j;
      int s0 = csr_src[start + j];
      acc_bf8(l1, h1, *(const uint4*)(hcol + (size_t)s0 * 64));
      if (rem > 1) {
        int s1 = csr_src[start + j + 1];
        acc_bf8(l2, h2, *(const uint4*)(hcol + (size_t)s1 * 64));
      }
      if (rem > 2) {
        int s2 = csr_src[start + j + 2];
        acc_bf8(l3, h3, *(const uint4*)(hcol + (size_t)s2 * 64));
      }
    }
    float4 alo = make_float4((l0.x + l1.x) + (l2.x + l3.x),
                             (l0.y + l1.y) + (l2.y + l3.y),
                             (l0.z + l1.z) + (l2.z + l3.z),
                             (l0.w + l1.w) + (l2.w + l3.w));
    float4 ahi = make_float4((h0.x + h1.x) + (h2.x + h3.x),
                             (h0.y + h1.y) + (h2.y + h3.y),
                             (h0.z + h1.z) + (h2.z + h3.z),
                             (h0.w + h1.w) + (h2.w + h3.w));
    alo.x += __shfl_xor(alo.x, 8); alo.y += __shfl_xor(alo.y, 8);
    alo.z += __shfl_xor(alo.z, 8); alo.w += __shfl_xor(alo.w, 8);
    ahi.x += __shfl_xor(ahi.x, 8); ahi.y += __shfl_xor(ahi.y, 8);
    ahi.z += __shfl_xor(ahi.z, 8); ahi.w += __shfl_xor(ahi.w, 8);
    dnode = dinv[node];
    if (half == 0) {
      float4 blo = *(const float4*)(bias + c8);
      float4 bhi = *(const float4*)(bias + c8 + 4);
      float4 vlo = make_float4(fmaxf(fmaf(dnode, alo.x, blo.x), 0.f),
                               fmaxf(fmaf(dnode, alo.y, blo.y), 0.f),
                               fmaxf(fmaf(dnode, alo.z, blo.z), 0.f),
                               fmaxf(fmaf(dnode, alo.w, blo.w), 0.f));
      float4 vhi = make_float4(fmaxf(fmaf(dnode, ahi.x, bhi.x), 0.f),
                               fmaxf(fmaf(dnode, ahi.y, bhi.y), 0.f),
                               fmaxf(fmaf(dnode, ahi.z, bhi.z), 0.f),
                               fmaxf(fmaf(dnode, ahi.w, bhi.w), 0.f));
      *(float4*)(&vrow[g][c8]) = vlo;
      *(float4*)(&vrow[g][c8 + 4]) = vhi;
    }
  }
  if (valid) {
    const int cc = lane16 * 4;
    float4 a0 = make_float4(0.f, 0.f, 0.f, 0.f);
#pragma unroll
    for (int k = 0; k < 64; k += 4) {
      float4 rv = *(const float4*)(&vrow[g][k]);
      a0 = fma4(rv.x, *(const float4*)(Ws + (k + 0) * 64 + cc), a0);
      a0 = fma4(rv.y, *(const float4*)(Ws + (k + 1) * 64 + cc), a0);
      a0 = fma4(rv.z, *(const float4*)(Ws + (k + 2) * 64 + cc), a0);
      a0 = fma4(rv.w, *(const float4*)(Ws + (k + 3) * 64 + cc), a0);
    }
    uint2 packed;
    packed.x = bf16r(dnode * a0.x) | (bf16r(dnode * a0.y) << 16);
    packed.y = bf16r(dnode * a0.z) | (bf16r(dnode * a0.w) << 16);
    *(uint2*)(hout + (size_t)node * 64 + cc) = packed;
  }
}

// Fused layer 2->3: agg (64, relu, b) -> gemm (64->32) -> bf16.
// 8 lanes/node, 32 nodes/block, x4-unrolled gather. [R7 form]
__global__ __launch_bounds__(BLOCK) void fused_agg_gemm32(
    const unsigned short* __restrict__ hin, const int* __restrict__ csr_src,
    const int* __restrict__ offs, const int* __restrict__ cnt,
    const float* __restrict__ dinv, const float* __restrict__ bias,
    const float* __restrict__ Wn, unsigned short* __restrict__ hout, int n) {
  __shared__ float Ws[64 * 32];
  __shared__ float vrow[32][68];  // +4 pad
  for (int i = threadIdx.x * 4; i < 64 * 32; i += BLOCK * 4)
    *(float4*)(Ws + i) = *(const float4*)(Wn + i);
  __syncthreads();
  const int g = threadIdx.x >> 3;
  const int lane8 = threadIdx.x & 7;
  const int c8 = lane8 * 8;
  const int node = blockIdx.x * 32 + g;
  const bool valid = node < n;
  float dnode = 0.f;
  if (valid) {
    const int start = offs[node];
    const int cn = cnt[node];
    const unsigned short* hcol = hin + c8;
    float4 l0 = make_float4(0.f, 0.f, 0.f, 0.f), h0 = l0;
    float4 l1 = l0, h1 = l0, l2 = l0, h2 = l0, l3 = l0, h3 = l0;
    acc_bf8(l0, h0, *(const uint4*)(hcol + (size_t)node * 64));
    int j = 0;
    for (; j + 4 <= cn; j += 4) {
      int s0 = csr_src[start + j + 0];
      int s1 = csr_src[start + j + 1];
      int s2 = csr_src[start + j + 2];
      int s3 = csr_src[start + j + 3];
      uint4 u0 = *(const uint4*)(hcol + (size_t)s0 * 64);
      uint4 u1 = *(const uint4*)(hcol + (size_t)s1 * 64);
      uint4 u2 = *(const uint4*)(hcol + (size_t)s2 * 64);
      uint4 u3 = *(const uint4*)(hcol + (size_t)s3 * 64);
      acc_bf8(l0, h0, u0);
      acc_bf8(l1, h1, u1);
      acc_bf8(l2, h2, u2);
      acc_bf8(l3, h3, u3);
    }
    if (j + 2 <= cn) {
      int s0 = csr_src[start + j + 0];
      int s1 = csr_src[start + j + 1];
      uint4 u0 = *(const uint4*)(hcol + (size_t)s0 * 64);
      uint4 u1 = *(const uint4*)(hcol + (size_t)s1 * 64);
      acc_bf8(l1, h1, u0);
      acc_bf8(l2, h2, u1);
      j += 2;
    }
    if (j < cn) {
      int s0 = csr_src[start + j];
      acc_bf8(l3, h3, *(const uint4*)(hcol + (size_t)s0 * 64));
    }
    float4 alo = make_float4((l0.x + l1.x) + (l2.x + l3.x),
                             (l0.y + l1.y) + (l2.y + l3.y),
                             (l0.z + l1.z) + (l2.z + l3.z),
                             (l0.w + l1.w) + (l2.w + l3.w));
    float4 ahi = make_float4((h0.x + h1.x) + (h2.x + h3.x),
                             (h0.y + h1.y) + (h2.y + h3.y),
                             (h0.z + h1.z) + (h2.z + h3.z),
                             (h0.w + h1.w) + (h2.w + h3.w));
    dnode = dinv[node];
    float4 blo = *(const float4*)(bias + c8);
    float4 bhi = *(const float4*)(bias + c8 + 4);
    float4 vlo = make_float4(fmaxf(fmaf(dnode, alo.x, blo.x), 0.f),
                             fmaxf(fmaf(dnode, alo.y, blo.y), 0.f),
                             fmaxf(fmaf(dnode, alo.z, blo.z), 0.f),
                             fmaxf(fmaf(dnode, alo.w, blo.w), 0.f));
    float4 vhi = make_float4(fmaxf(fmaf(dnode, ahi.x, bhi.x), 0.f),
                             fmaxf(fmaf(dnode, ahi.y, bhi.y), 0.f),
                             fmaxf(fmaf(dnode, ahi.z, bhi.z), 0.f),
                             fmaxf(fmaf(dnode, ahi.w, bhi.w), 0.f));
    *(float4*)(&vrow[g][c8]) = vlo;
    *(float4*)(&vrow[g][c8 + 4]) = vhi;
  }
  if (valid) {
    const int cc = lane8 * 4;
    float4 a0 = make_float4(0.f, 0.f, 0.f, 0.f);
#pragma unroll
    for (int k = 0; k < 64; k += 4) {
      float4 rv = *(const float4*)(&vrow[g][k]);
      a0 = fma4(rv.x, *(const float4*)(Ws + (k + 0) * 32 + cc), a0);
      a0 = fma4(rv.y, *(const float4*)(Ws + (k + 1) * 32 + cc), a0);
      a0 = fma4(rv.z, *(const float4*)(Ws + (k + 2) * 32 + cc), a0);
      a0 = fma4(rv.w, *(const float4*)(Ws + (k + 3) * 32 + cc), a0);
    }
    uint2 packed;
    packed.x = bf16r(dnode * a0.x) | (bf16r(dnode * a0.y) << 16);
    packed.y = bf16r(dnode * a0.z) | (bf16r(dnode * a0.w) << 16);
    *(uint2*)(hout + (size_t)node * 32 + cc) = packed;
  }
}

// Final aggregation (F=32, no relu): 4 lanes/node, 64 nodes/block. [R7 form]
__global__ __launch_bounds__(BLOCK) void agg3_kernel(
    const unsigned short* __restrict__ hbf, const int* __restrict__ csr_src,
    const int* __restrict__ offs, const int* __restrict__ cnt,
    const float* __restrict__ dinv, const float* __restrict__ bias,
    float* __restrict__ out, int n) {
  constexpr int F = 32;
  const int node = blockIdx.x * 64 + (int)(threadIdx.x >> 2);
  const int c8 = (threadIdx.x & 3) * 8;
  if (node >= n) return;
  const int start = offs[node];
  const int cn = cnt[node];
  const unsigned short* hcol = hbf + c8;
  float4 l0 = make_float4(0.f, 0.f, 0.f, 0.f), h0 = l0;
  float4 l1 = l0, h1 = l0, l2 = l0, h2 = l0, l3 = l0, h3 = l0;
  acc_bf8(l0, h0, *(const uint4*)(hcol + (size_t)node * F));
  int j = 0;
  for (; j + 4 <= cn; j += 4) {
    int s0 = csr_src[start + j + 0];
    int s1 = csr_src[start + j + 1];
    int s2 = csr_src[start + j + 2];
    int s3 = csr_src[start + j + 3];
    uint4 u0 = *(const uint4*)(hcol + (size_t)s0 * F);
    uint4 u1 = *(const uint4*)(hcol + (size_t)s1 * F);
    uint4 u2 = *(const uint4*)(hcol + (size_t)s2 * F);
    uint4 u3 = *(const uint4*)(hcol + (size_t)s3 * F);
    acc_bf8(l0, h0, u0);
    acc_bf8(l1, h1, u1);
    acc_bf8(l2, h2, u2);
    acc_bf8(l3, h3, u3);
  }
  if (j + 2 <= cn) {
    int s0 = csr_src[start + j + 0];
    int s1 = csr_src[start + j + 1];
    uint4 u0 = *(const uint4*)(hcol + (size_t)s0 * F);
    uint4 u1 = *(const uint4*)(hcol + (size_t)s1 * F);
    acc_bf8(l1, h1, u0);
    acc_bf8(l2, h2, u1);
    j += 2;
  }
  if (j < cn) {
    int s0 = csr_src[start + j];
    acc_bf8(l3, h3, *(const uint4*)(hcol + (size_t)s0 * F));
  }
  float4 alo = make_float4((l0.x + l1.x) + (l2.x + l3.x),
                           (l0.y + l1.y) + (l2.y + l3.y),
                           (l0.z + l1.z) + (l2.z + l3.z),
                           (l0.w + l1.w) + (l2.w + l3.w));
  float4 ahi = make_float4((h0.x + h1.x) + (h2.x + h3.x),
                           (h0.y + h1.y) + (h2.y + h3.y),
                           (h0.z + h1.z) + (h2.z + h3.z),
                           (h0.w + h1.w) + (h2.w + h3.w));
  float d = dinv[node];
  float4 blo = *(const float4*)(bias + c8);
  float4 bhi = *(const float4*)(bias + c8 + 4);
  f32x4 vlo = {fmaf(d, alo.x, blo.x), fmaf(d, alo.y, blo.y),
               fmaf(d, alo.z, blo.z), fmaf(d, alo.w, blo.w)};
  f32x4 vhi = {fmaf(d, ahi.x, bhi.x), fmaf(d, ahi.y, bhi.y),
               fmaf(d, ahi.z, bhi.z), fmaf(d, ahi.w, bhi.w)};
  float* op = out + (size_t)node * F + c8;
  __builtin_nontemporal_store(vlo, (f32x4*)op);
  __builtin_nontemporal_store(vhi, (f32x4*)(op + 4));
}

static inline size_t align_up(size_t v, size_t a) { return (v + a - 1) & ~(a - 1); }

extern "C" void kernel_launch(void* const* d_in, const int* in_sizes, int n_in,
                              void* d_out, int out_size, void* d_ws, size_t ws_size,
                              hipStream_t stream) {
  const float* x = (const float*)d_in[0];
  const int* edge_index = (const int*)d_in[1];
  const float* W1 = (const float*)d_in[2];
  const float* b1 = (const float*)d_in[3];
  const float* W2 = (const float*)d_in[4];
  const float* b2 = (const float*)d_in[5];
  const float* W3 = (const float*)d_in[6];
  const float* b3 = (const float*)d_in[7];
  float* out = (float*)d_out;

  const int n = in_sizes[0] / 64;       // 100000
  const int e = in_sizes[1] / 2;        // 1600000
  const int* e_src = edge_index;
  const int* e_dst = edge_index + e;
  const int npb = (n + NBUCKET - 1) / NBUCKET;  // 196

  char* ws = (char*)d_ws;
  size_t off = 0;
  int* bcursor = (int*)(ws + off); off = align_up(off + NBUCKET * 4, 512);
  int* offs    = (int*)(ws + off); off = align_up(off + (size_t)n * 4, 512);
  int* cnt     = (int*)(ws + off); off = align_up(off + (size_t)n * 4, 512);
  float* dinv  = (float*)(ws + off); off = align_up(off + (size_t)n * 4, 512);
  int* binned  = (int*)(ws + off); off = align_up(off + (size_t)NBUCKET * SLOT * 4, 512);
  int* csr_src = (int*)(ws + off); off = align_up(off + (size_t)NBUCKET * SLOT * 4, 512);
  unsigned short* hbuf_a = (unsigned short*)(ws + off);
  off = align_up(off + (size_t)n * 64 * 2, 512);
  unsigned short* hbuf_b = (unsigned short*)(ws + off);
  off = align_up(off + (size_t)n * 64 * 2, 512);
  (void)ws_size;

  const int gC = (e + CHUNK - 1) / CHUNK;

  hipMemsetAsync(bcursor, 0, NBUCKET * 4, stream);
  binning_kernel<<<gC, BLOCK, 0, stream>>>(e_src, e_dst, bcursor, binned, e, npb);
  bucket_build<<<NBUCKET, BLOCK, 0, stream>>>(binned, bcursor, offs, cnt, dinv,
                                              csr_src, n, npb);

  gemm1_kernel<<<(n + 15) / 16, BLOCK, 0, stream>>>(x, W1, dinv, hbuf_a, n);
  fused_agg_gemm64<<<(n + 15) / 16, BLOCK, 0, stream>>>(
      hbuf_a, csr_src, offs, cnt, dinv, b1, W2, hbuf_b, n);
  fused_agg_gemm32<<<(n + 31) / 32, BLOCK, 0, stream>>>(
      hbuf_b, csr_src, offs, cnt, dinv, b2, W3, hbuf_a, n);
  agg3_kernel<<<(n + 63) / 64, BLOCK, 0, stream>>>(hbuf_a, csr_src, offs, cnt,
                                                   dinv, b3, out, n);
}